// Round 13
// baseline (3376.259 us; speedup 1.0000x reference)
//
#include <hip/hip_runtime.h>
#include <hip/hip_bf16.h>
#include <stdint.h>

// Problem dims
#define B_  32
#define T_  512
#define E_  256
#define H_  512
#define K_  17
// 4H = 2048

typedef unsigned short us;
typedef __attribute__((ext_vector_type(8))) short short8;
typedef __attribute__((ext_vector_type(4))) float f32x4;

__device__ __forceinline__ float bf2f(unsigned int u16) {
    union { unsigned int i; float f; } v; v.i = u16 << 16; return v.f;
}
__device__ __forceinline__ us f2bf(float f) {
    union { float f; unsigned int i; } v; v.f = f;
    unsigned int b = v.i;
    return (us)((b + 0x7FFFu + ((b >> 16) & 1u)) >> 16);
}
__device__ __forceinline__ float sigf(float x) { return 1.0f / (1.0f + __expf(-x)); }
__device__ __forceinline__ float tanhf_(float x) { return 1.0f - 2.0f / (__expf(2.0f * x) + 1.0f); }

// ---------------------------------------------------------------------------
// Kernel 0: float32 -> bf16 conversion (RNE), 4 elements/thread.
__global__ void k_cvt(const float* __restrict__ src, us* __restrict__ dst, int n4) {
    int i = blockIdx.x * 256 + threadIdx.x;
    if (i < n4) {
        float4 v = ((const float4*)src)[i];
        uint2 p;
        p.x = (uint32_t)f2bf(v.x) | ((uint32_t)f2bf(v.y) << 16);
        p.y = (uint32_t)f2bf(v.z) | ((uint32_t)f2bf(v.w) << 16);
        ((uint2*)dst)[i] = p;
    }
}

// ---------------------------------------------------------------------------
// Kernel 1: sentinel + marker/slot init + gathered token-index table.
// ids2 layout: [dir][t*B + b].  flags: 2 dirs x 32 wgs x 4 wave-slots,
// each slot 64 B apart (w*64 + wv*16 ints).
__global__ void k_init(const int* __restrict__ ids, const int* __restrict__ lengths,
                       int* __restrict__ ids2, int* __restrict__ marker,
                       int* __restrict__ flags, float* __restrict__ out) {
    int idx = blockIdx.x * 256 + threadIdx.x;
    if (idx == 0) { *marker = 1; out[0] = -3328.0f; }
    if (idx < 4096) flags[idx] = 0;
    if (idx < 2 * B_ * T_) {
        int dir = idx >> 14;           // 16384 per dir
        int r   = idx & 16383;
        int t   = r >> 5;              // t-major, B=32
        int b   = r & 31;
        int l   = lengths[b];
        int tt  = (dir == 0) ? t : ((t < l) ? (l - 1 - t) : t);
        ids2[idx] = ids[b * T_ + tt];
    }
}

// ---------------------------------------------------------------------------
// Kernel 2: xg[dir][t*B+b][jg] = (emb[ids2] @ W_ih^T + bias), permuted layout
// jg = j*4 + g  (torch gates i,f,g,o contiguous per hidden index j).
__launch_bounds__(256)
__global__ void k_xg(const us* __restrict__ emb,
                     const us* __restrict__ wf, const float* __restrict__ bfv,
                     const us* __restrict__ wb, const float* __restrict__ bbv,
                     const int* __restrict__ ids2, us* __restrict__ xg,
                     int* __restrict__ marker) {
    if (blockIdx.x == 0 && blockIdx.y == 0 && blockIdx.z == 0 && threadIdx.x == 0)
        atomicOr(marker, 2);
    int mt = blockIdx.x, nt = blockIdx.y, dir = blockIdx.z;
    const us* W      = dir ? wb  : wf;
    const float* bias = dir ? bbv : bfv;
    const int* id2 = ids2 + dir * (B_ * T_);
    us* xgd = xg + (size_t)dir * B_ * T_ * 2048;
    int m0 = mt * 64, n0 = nt * 64;
    __shared__ __align__(16) us As[64][136];
    __shared__ __align__(16) us Bs[64][136];
    int tid = threadIdx.x;
    int wv = tid >> 6, lane = tid & 63;
    int lm = lane & 15, lg = lane >> 4;
    f32x4 z = {0.f, 0.f, 0.f, 0.f};
    f32x4 acc[4] = {z, z, z, z};
    for (int half = 0; half < 2; ++half) {
        for (int c = tid; c < 1024; c += 256) {
            int row = c >> 4, cb = c & 15;
            int mg = m0 + row;
            int j = mg >> 2, g = mg & 3;
            *(uint4*)&As[row][cb * 8] =
                *(const uint4*)(W + ((size_t)(g * H_ + j)) * E_ + half * 128 + cb * 8);
            int gi = id2[n0 + row];
            *(uint4*)&Bs[row][cb * 8] =
                *(const uint4*)(emb + (size_t)gi * E_ + half * 128 + cb * 8);
        }
        __syncthreads();
#pragma unroll
        for (int kt = 0; kt < 4; ++kt) {
            short8 a = *(const short8*)&As[wv * 16 + lm][kt * 32 + lg * 8];
#pragma unroll
            for (int n2 = 0; n2 < 4; ++n2) {
                short8 b = *(const short8*)&Bs[n2 * 16 + lm][kt * 32 + lg * 8];
                acc[n2] = __builtin_amdgcn_mfma_f32_16x16x32_bf16(a, b, acc[n2], 0, 0, 0);
            }
        }
        __syncthreads();
    }
    int jgb = m0 + wv * 16 + lg * 4;
    int j = jgb >> 2;
#pragma unroll
    for (int n2 = 0; n2 < 4; ++n2) {
        int token = n0 + n2 * 16 + lm;
        us p[4];
#pragma unroll
        for (int q = 0; q < 4; ++q)
            p[q] = f2bf(acc[n2][q] + bias[q * H_ + j]);
        uint2 pv;
        pv.x = (uint32_t)p[0] | ((uint32_t)p[1] << 16);
        pv.y = (uint32_t)p[2] | ((uint32_t)p[3] << 16);
        *(uint2*)(xgd + (size_t)token * 2048 + jgb) = pv;
    }
}

// ---------------------------------------------------------------------------
// Kernel 3: persistent BiLSTM — single-barrier step, per-wave slot release.
// 64 wgs: dir=bid>>5, slice w=bid&31. W slice 64 KB LDS (XOR-swizzled).
// Per step: [wave0 polls 128 wave-slots -> barrier] -> h u64 atomic loads ->
// unpack xg (prefetched regs) -> MFMA -> cell -> in-register wave transpose
// (4 shfl) -> 16B-segment publish -> wave-local vmcnt(0) -> own wave-slot ->
// hod stores + next-xg prefetch (fly under next poll window).
__launch_bounds__(256)
__global__ void k_lstm(const us* __restrict__ whf, const us* __restrict__ whb,
                       const us* __restrict__ xg,
                       us* __restrict__ h_state, us* __restrict__ h_out,
                       int* __restrict__ flags, int* __restrict__ marker) {
    int bid = blockIdx.x;
    int dir = bid >> 5, w = bid & 31;
    int tid = threadIdx.x;
    if (bid == 0 && tid == 0) atomicOr(marker, 4);
    const us* Wg = dir ? whb : whf;
    __shared__ __align__(16) us Ws[64 * 512];   // 65536 B, swizzled
    for (int c = tid; c < 4096; c += 256) {      // 4096 x 16B chunks
        int row = c >> 6, cb = c & 63;
        int rt = row >> 4, rl = row & 15;
        int jj = rl >> 2, g = rl & 3;
        int srcRow = g * H_ + w * 16 + rt * 4 + jj;
        uint4 v = *(const uint4*)(Wg + (size_t)srcRow * H_ + cb * 8);
        int lb = row * 1024 + ((cb * 16) ^ ((row & 7) << 4));
        *(uint4*)((char*)Ws + lb) = v;
    }
    __syncthreads();
    int wv = tid >> 6, lane = tid & 63;
    int nb = wv & 1, rh = wv >> 1;               // batch-half, row-half
    int lm = lane & 15, lg = lane >> 4;
    int b = nb * 16 + lm;                        // this lane's batch (N index)
    int jl0 = rh * 8 + lg;                       // ti=0 local j
    int jl1 = rh * 8 + 4 + lg;                   // ti=1 local j
    const us* xgd = xg + (size_t)dir * B_ * T_ * 2048;
    us* hod = h_out + (size_t)dir * B_ * T_ * H_;
    int* slots = flags + dir * 2048;             // 32 wgs x 4 wave-slots, 64B apart
    const uint64_t* hbase = (const uint64_t*)h_state + (size_t)dir * 8192;
    uint32_t* hw32 = (uint32_t*)h_state + (size_t)dir * 16384;
    // transpose targets (per lane): holds u32 for (bt, pair p)
    int bl = lane >> 2, p = lane & 3;
    int sA = bl + ((p & 1) << 5);                // source lane for lo element
    int sB = sA + 16;                            // source lane for hi element
    int bt = nb * 16 + bl;
    uint32_t* hwp_base = hw32 + (size_t)bt * 256 + w * 8 + rh * 4 + p;
    // poll indices (wave 0): q = lane and q = lane+64 over 128 wave-slots
    int pi1 = (lane >> 2) * 64 + (lane & 3) * 16;
    int pi2 = ((lane + 64) >> 2) * 64 + (lane & 3) * 16;
    float cc0 = 0.f, cc1 = 0.f;
    bool alive = true;
    // prologue: prefetch xg for t=0
    uint2 vr0 = *(const uint2*)(xgd + ((size_t)b) * 2048 + (w * 16 + jl0) * 4);
    uint2 vr1 = *(const uint2*)(xgd + ((size_t)b) * 2048 + (w * 16 + jl1) * 4);
#pragma unroll 1
    for (int t = 0; t < T_; ++t) {
        f32x4 acc[2];
        if (t > 0) {
            if (wv == 0) {                       // wave 0: poll all 128 wave-slots
                int polls = 0;
                for (;;) {
                    int v1 = __hip_atomic_load(&slots[pi1], __ATOMIC_RELAXED, __HIP_MEMORY_SCOPE_AGENT);
                    int v2 = __hip_atomic_load(&slots[pi2], __ATOMIC_RELAXED, __HIP_MEMORY_SCOPE_AGENT);
                    if (__all(v1 >= t && v2 >= t) || !alive) break;
                    __builtin_amdgcn_s_sleep(1);
                    if (++polls > 300000) {      // fail loud, not hung
                        if (lane == 0) atomicOr(marker, 32);
                        alive = false;
                    }
                }
            }
            __syncthreads();                     // the ONLY barrier per step
            // coherent h_{t-1} loads (u64 AGENT atomics = L2-bypass)
            const uint64_t* hp = hbase + ((t - 1) & 1) * 4096 + (size_t)b * 128 + lg * 2;
            uint64_t hv[32];
#pragma unroll
            for (int kt = 0; kt < 16; ++kt) {
                hv[2 * kt]     = __hip_atomic_load(hp + kt * 8,     __ATOMIC_RELAXED, __HIP_MEMORY_SCOPE_AGENT);
                hv[2 * kt + 1] = __hip_atomic_load(hp + kt * 8 + 1, __ATOMIC_RELAXED, __HIP_MEMORY_SCOPE_AGENT);
            }
            // unpack xg (registers, prefetched) under the load shadow
            acc[0][0] = bf2f(vr0.x & 0xffff); acc[0][1] = bf2f(vr0.x >> 16);
            acc[0][2] = bf2f(vr0.y & 0xffff); acc[0][3] = bf2f(vr0.y >> 16);
            acc[1][0] = bf2f(vr1.x & 0xffff); acc[1][1] = bf2f(vr1.x >> 16);
            acc[1][2] = bf2f(vr1.y & 0xffff); acc[1][3] = bf2f(vr1.y >> 16);
#pragma unroll
            for (int ti = 0; ti < 2; ++ti) {
                int r0 = (rh * 2 + ti) * 16 + lm;
                const char* abase = (const char*)Ws + r0 * 1024;
                int sw = (r0 & 7) << 4;
#pragma unroll
                for (int kt = 0; kt < 16; ++kt) {
                    union { uint64_t u[2]; short8 s; } bu;
                    bu.u[0] = hv[2 * kt]; bu.u[1] = hv[2 * kt + 1];
                    short8 a = *(const short8*)(abase + ((kt * 64 + lg * 16) ^ sw));
                    acc[ti] = __builtin_amdgcn_mfma_f32_16x16x32_bf16(a, bu.s, acc[ti], 0, 0, 0);
                }
            }
        } else {
            acc[0][0] = bf2f(vr0.x & 0xffff); acc[0][1] = bf2f(vr0.x >> 16);
            acc[0][2] = bf2f(vr0.y & 0xffff); acc[0][3] = bf2f(vr0.y >> 16);
            acc[1][0] = bf2f(vr1.x & 0xffff); acc[1][1] = bf2f(vr1.x >> 16);
            acc[1][2] = bf2f(vr1.y & 0xffff); acc[1][3] = bf2f(vr1.y >> 16);
        }
        // cell update (acc[ti][q]: q = gate, torch order i,f,g,o)
        cc0 = sigf(acc[0][1]) * cc0 + sigf(acc[0][0]) * tanhf_(acc[0][2]);
        float h0 = sigf(acc[0][3]) * tanhf_(cc0);
        cc1 = sigf(acc[1][1]) * cc1 + sigf(acc[1][0]) * tanhf_(cc1 * 0.0f + acc[1][2]);
        float h1 = sigf(acc[1][3]) * tanhf_(cc1);
        us p0 = f2bf(h0), p1 = f2bf(h1);
        // in-register wave transpose: lane L gets u32 for (bt=L>>2, pair=L&3)
        int a0 = __shfl((int)p0, sA), a1 = __shfl((int)p0, sB);
        int c0v = __shfl((int)p1, sA), c1v = __shfl((int)p1, sB);
        uint32_t lo = (p < 2) ? (uint32_t)(us)a0 : (uint32_t)(us)c0v;
        uint32_t hi = (p < 2) ? (uint32_t)(us)a1 : (uint32_t)(us)c1v;
        atomicExch(hwp_base + (size_t)(t & 1) * 8192, lo | (hi << 16));
        asm volatile("s_waitcnt vmcnt(0)" ::: "memory");   // wave-local drain
        __builtin_amdgcn_sched_barrier(0);
        if (lane == 0) atomicExch(&slots[w * 64 + wv * 16], t + 1);
        __builtin_amdgcn_sched_barrier(0);
        // off-critical-path: h_out stores + next-step xg prefetch
        hod[((size_t)b * T_ + t) * H_ + w * 16 + jl0] = p0;
        hod[((size_t)b * T_ + t) * H_ + w * 16 + jl1] = p1;
        if (t + 1 < T_) {
            vr0 = *(const uint2*)(xgd + ((size_t)((t + 1) * 32 + b)) * 2048 + (w * 16 + jl0) * 4);
            vr1 = *(const uint2*)(xgd + ((size_t)((t + 1) * 32 + b)) * 2048 + (w * 16 + jl1) * 4);
        }
    }
}

// ---------------------------------------------------------------------------
// Kernel 4: emissions[b*T+t][k] = [hf(b,t), hb(b,rev)] . w_cls[k] + b_cls[k]
__launch_bounds__(256)
__global__ void k_emis(const us* __restrict__ h_out,
                       const us* __restrict__ wcls, const float* __restrict__ bcls,
                       const int* __restrict__ lengths, float* __restrict__ emis,
                       int* __restrict__ marker) {
    if (blockIdx.x == 0 && threadIdx.x == 0) atomicOr(marker, 8);
    __shared__ __align__(8) us Wc[17][1032];
    int tid = threadIdx.x;
    for (int c = tid; c < 17 * 256; c += 256) {
        int row = c >> 8; int c4 = (c & 255) * 4;
        *(uint2*)&Wc[row][c4] = *(const uint2*)(wcls + (size_t)row * 1024 + c4);
    }
    __syncthreads();
    int i = blockIdx.x * 8 + (tid >> 5);
    int k = tid & 31;
    int b = i >> 9, t = i & 511;
    int l = lengths[b];
    int trv = (t < l) ? (l - 1 - t) : t;
    const us* hf = h_out + ((size_t)(0 * B_ + b) * T_ + t) * H_;
    const us* hb = h_out + ((size_t)(1 * B_ + b) * T_ + trv) * H_;
    if (k < K_) {
        float acc = bcls[k];
        for (int e = 0; e < H_; e += 4) {
            uint2 hv = *(const uint2*)(hf + e);
            uint2 wv = *(const uint2*)&Wc[k][e];
            acc = fmaf(bf2f(hv.x & 0xffff), bf2f(wv.x & 0xffff), acc);
            acc = fmaf(bf2f(hv.x >> 16),    bf2f(wv.x >> 16),    acc);
            acc = fmaf(bf2f(hv.y & 0xffff), bf2f(wv.y & 0xffff), acc);
            acc = fmaf(bf2f(hv.y >> 16),    bf2f(wv.y >> 16),    acc);
        }
        for (int e = 0; e < H_; e += 4) {
            uint2 hv = *(const uint2*)(hb + e);
            uint2 wv = *(const uint2*)&Wc[k][512 + e];
            acc = fmaf(bf2f(hv.x & 0xffff), bf2f(wv.x & 0xffff), acc);
            acc = fmaf(bf2f(hv.x >> 16),    bf2f(wv.x >> 16),    acc);
            acc = fmaf(bf2f(hv.y & 0xffff), bf2f(wv.y & 0xffff), acc);
            acc = fmaf(bf2f(hv.y >> 16),    bf2f(wv.y >> 16),    acc);
        }
        emis[(size_t)i * 20 + k] = acc;
    }
}

// ---------------------------------------------------------------------------
// Kernel 5: CRF per batch, 1 wave, register-resident forward recursion.
__global__ void k_crf(const float* __restrict__ emis, const int* __restrict__ tags,
                      const int* __restrict__ lengths,
                      const float* __restrict__ start_t, const float* __restrict__ trans_t,
                      const float* __restrict__ end_t, float* __restrict__ res,
                      int* __restrict__ marker) {
    if (blockIdx.x == 0 && threadIdx.x == 0) atomicOr(marker, 16);
    __shared__ float tr[17][18];
    int b = blockIdx.x, tid = threadIdx.x;
    for (int i = tid; i < 289; i += 64) tr[i / 17][i % 17] = trans_t[i];
    __syncthreads();
    int l = lengths[b];
    const int* tg = tags + b * T_;
    const float* eb = emis + (size_t)b * T_ * 20;
    float sn = 0.f;
    for (int t = tid; t < T_; t += 64) {
        if (t < l) {
            sn += eb[t * 20 + tg[t]];
            if (t >= 1) sn += tr[tg[t - 1]][tg[t]];
        }
    }
#pragma unroll
    for (int off = 32; off; off >>= 1) sn += __shfl_xor(sn, off, 64);
    float numer = sn + start_t[tg[0]] + end_t[tg[l - 1]];
    int k = (tid < K_) ? tid : (K_ - 1);
    float trc[17];
#pragma unroll
    for (int j = 0; j < 17; ++j) trc[j] = trans_t[j * 17 + k];
    float alpha = start_t[k] + eb[k];
    for (int t = 1; t < l; ++t) {
        float av[17];
        float m = -1e30f;
#pragma unroll
        for (int j = 0; j < 17; ++j) {
            av[j] = __shfl(alpha, j) + trc[j];
            m = fmaxf(m, av[j]);
        }
        float s = 0.f;
#pragma unroll
        for (int j = 0; j < 17; ++j) s += __expf(av[j] - m);
        alpha = m + __logf(s) + eb[t * 20 + k];
    }
    float v = (tid < K_) ? (alpha + end_t[tid]) : -1e30f;
    float m2 = v;
#pragma unroll
    for (int off = 32; off; off >>= 1) m2 = fmaxf(m2, __shfl_xor(m2, off, 64));
    float s2 = __expf(v - m2);
#pragma unroll
    for (int off = 32; off; off >>= 1) s2 += __shfl_xor(s2, off, 64);
    if (tid == 0) res[b] = numer - (m2 + __logf(s2));
}

// ---------------------------------------------------------------------------
// Kernel 6 (LAST): float32 output, negative diagnostic codes:
//   hm!=0 -> -(16384+512*hm) ; dm!=31 -> -(8192+128*(dm&63)) ;
//   NaN in res[b] -> -(4096+b) ; else loss (positive ~1048).
__global__ void k_fin(const float* __restrict__ res, int* __restrict__ marker,
                      int hostmask, float* __restrict__ out) {
    int tid = threadIdx.x;
    if (hostmask != 0) {
        if (tid == 0) out[0] = -(16384.0f + 512.0f * (float)hostmask);
        return;
    }
    int dm = atomicOr(marker, 0);
    if (dm != 31) {
        if (tid == 0) out[0] = -(8192.0f + 128.0f * (float)(dm & 63));
        return;
    }
    float v = (tid < B_) ? res[tid] : 0.f;
    unsigned long long nb = __ballot(v != v);
    if (nb != 0ULL) {
        if (tid == 0) out[0] = -(4096.0f + (float)(__ffsll((long long)nb) - 1));
        return;
    }
#pragma unroll
    for (int off = 32; off; off >>= 1) v += __shfl_xor(v, off, 64);
    if (tid == 0) out[0] = -(v / (float)B_);
}

// ---------------------------------------------------------------------------
extern "C" void kernel_launch(void* const* d_in, const int* in_sizes, int n_in,
                              void* d_out, int out_size, void* d_ws, size_t ws_size,
                              hipStream_t stream) {
    const int* ids      = (const int*)d_in[0];
    const int* lengths  = (const int*)d_in[1];
    const int* tags     = (const int*)d_in[2];
    // d_in[3] = mask (recomputed from lengths)
    const float* emb_f  = (const float*)d_in[4];
    const float* wihf_f = (const float*)d_in[5];
    const float* whhf_f = (const float*)d_in[6];
    const float* bfv    = (const float*)d_in[7];
    const float* wihb_f = (const float*)d_in[8];
    const float* whhb_f = (const float*)d_in[9];
    const float* bbv    = (const float*)d_in[10];
    const float* wcls_f = (const float*)d_in[11];
    const float* bcls   = (const float*)d_in[12];
    const float* start  = (const float*)d_in[13];
    const float* trans  = (const float*)d_in[14];
    const float* endt   = (const float*)d_in[15];
    float* out = (float*)d_out;

    // host-side validation (element counts)
    int hm = 0;
    if (n_in != 16 || out_size != 1) hm |= 8;
    const int exp_sz[16] = {
        16384, 32, 16384, 16384,
        12800000,
        524288, 1048576, 2048,
        524288, 1048576, 2048,
        17408, 17,
        17, 289, 17
    };
    if (!(hm & 8))
        for (int i = 0; i < 16; ++i)
            if (in_sizes[i] != exp_sz[i]) hm |= 2;

    // workspace carve (256B aligned)
    char* w = (char*)d_ws;
    size_t off = 0;
    auto carve = [&](size_t bytes) { void* p = w + off; off += (bytes + 255) & ~(size_t)255; return p; };
    int* ids2    = (int*)carve((size_t)2 * B_ * T_ * 4);
    int* marker  = (int*)carve(256);
    int* flags   = (int*)carve(16384);           // 2 dirs x 32 wgs x 4 wave-slots, 64B apart
    float* res   = (float*)carve(256);
    float* emis  = (float*)carve((size_t)B_ * T_ * 20 * 4);
    us* xg       = (us*)carve((size_t)2 * B_ * T_ * 2048 * 2);
    us* h_st     = (us*)carve((size_t)2 * 2 * B_ * H_ * 2);
    us* h_out    = (us*)carve((size_t)2 * B_ * T_ * H_ * 2);
    us* emb_b    = (us*)carve((size_t)12800000 * 2);
    us* wihf_b   = (us*)carve((size_t)524288 * 2);
    us* wihb_b   = (us*)carve((size_t)524288 * 2);
    us* whhf_b   = (us*)carve((size_t)1048576 * 2);
    us* whhb_b   = (us*)carve((size_t)1048576 * 2);
    us* wcls_b   = (us*)carve((size_t)17408 * 2);
    if (off > ws_size) hm |= 4;

    (void)hipGetLastError();
    if ((hm & (2 | 4 | 8)) == 0) {
        k_init<<<(2 * B_ * T_ + 255) / 256, 256, 0, stream>>>(ids, lengths, ids2, marker, flags, out);
        // f32 -> bf16 conversions
        k_cvt<<<(12800000 / 4 + 255) / 256, 256, 0, stream>>>(emb_f,  emb_b,  12800000 / 4);
        k_cvt<<<(524288   / 4 + 255) / 256, 256, 0, stream>>>(wihf_f, wihf_b, 524288 / 4);
        k_cvt<<<(524288   / 4 + 255) / 256, 256, 0, stream>>>(wihb_f, wihb_b, 524288 / 4);
        k_cvt<<<(1048576  / 4 + 255) / 256, 256, 0, stream>>>(whhf_f, whhf_b, 1048576 / 4);
        k_cvt<<<(1048576  / 4 + 255) / 256, 256, 0, stream>>>(whhb_f, whhb_b, 1048576 / 4);
        k_cvt<<<(17408    / 4 + 255) / 256, 256, 0, stream>>>(wcls_f, wcls_b, 17408 / 4);
        k_xg<<<dim3(2048 / 64, B_ * T_ / 64, 2), 256, 0, stream>>>(emb_b, wihf_b, bfv, wihb_b, bbv, ids2, xg, marker);
        k_lstm<<<64, 256, 0, stream>>>(whhf_b, whhb_b, xg, h_st, h_out, flags, marker);
        k_emis<<<B_ * T_ / 8, 256, 0, stream>>>(h_out, wcls_b, bcls, lengths, emis, marker);
        k_crf<<<B_, 64, 0, stream>>>(emis, tags, lengths, start, trans, endt, res, marker);
        if (hipGetLastError() != hipSuccess) hm |= 1;
    }
    k_fin<<<1, 64, 0, stream>>>(res, marker, hm, out);
}

// Round 14
// 3029.687 us; speedup vs baseline: 1.1144x; 1.1144x over previous
//
#include <hip/hip_runtime.h>
#include <hip/hip_bf16.h>
#include <stdint.h>

// Problem dims
#define B_  32
#define T_  512
#define E_  256
#define H_  512
#define K_  17
// 4H = 2048

typedef unsigned short us;
typedef __attribute__((ext_vector_type(8))) short short8;
typedef __attribute__((ext_vector_type(4))) float f32x4;

__device__ __forceinline__ float bf2f(unsigned int u16) {
    union { unsigned int i; float f; } v; v.i = u16 << 16; return v.f;
}
__device__ __forceinline__ us f2bf(float f) {
    union { float f; unsigned int i; } v; v.f = f;
    unsigned int b = v.i;
    return (us)((b + 0x7FFFu + ((b >> 16) & 1u)) >> 16);
}
__device__ __forceinline__ float sigf(float x) { return 1.0f / (1.0f + __expf(-x)); }
__device__ __forceinline__ float tanhf_(float x) { return 1.0f - 2.0f / (__expf(2.0f * x) + 1.0f); }

// ---------------------------------------------------------------------------
// Kernel 0: float32 -> bf16 conversion (RNE), 4 elements/thread.
__global__ void k_cvt(const float* __restrict__ src, us* __restrict__ dst, int n4) {
    int i = blockIdx.x * 256 + threadIdx.x;
    if (i < n4) {
        float4 v = ((const float4*)src)[i];
        uint2 p;
        p.x = (uint32_t)f2bf(v.x) | ((uint32_t)f2bf(v.y) << 16);
        p.y = (uint32_t)f2bf(v.z) | ((uint32_t)f2bf(v.w) << 16);
        ((uint2*)dst)[i] = p;
    }
}

// ---------------------------------------------------------------------------
// Kernel 1: sentinel + marker/slot init + gathered token-index table.
// ids2 layout: [dir][t*B + b]
__global__ void k_init(const int* __restrict__ ids, const int* __restrict__ lengths,
                       int* __restrict__ ids2, int* __restrict__ marker,
                       int* __restrict__ flags, float* __restrict__ out) {
    int idx = blockIdx.x * 256 + threadIdx.x;
    if (idx == 0) { *marker = 1; out[0] = -3328.0f; }
    if (idx < 1024) flags[idx] = 0;             // 2 dirs x 32 slots x 16-int pad
    if (idx < 2 * B_ * T_) {
        int dir = idx >> 14;           // 16384 per dir
        int r   = idx & 16383;
        int t   = r >> 5;              // t-major, B=32
        int b   = r & 31;
        int l   = lengths[b];
        int tt  = (dir == 0) ? t : ((t < l) ? (l - 1 - t) : t);
        ids2[idx] = ids[b * T_ + tt];
    }
}

// ---------------------------------------------------------------------------
// Kernel 2: xg[dir][t*B+b][jg] = (emb[ids2] @ W_ih^T + bias), permuted layout
// jg = j*4 + g  (torch gates i,f,g,o contiguous per hidden index j).
__launch_bounds__(256)
__global__ void k_xg(const us* __restrict__ emb,
                     const us* __restrict__ wf, const float* __restrict__ bfv,
                     const us* __restrict__ wb, const float* __restrict__ bbv,
                     const int* __restrict__ ids2, us* __restrict__ xg,
                     int* __restrict__ marker) {
    if (blockIdx.x == 0 && blockIdx.y == 0 && blockIdx.z == 0 && threadIdx.x == 0)
        atomicOr(marker, 2);
    int mt = blockIdx.x, nt = blockIdx.y, dir = blockIdx.z;
    const us* W      = dir ? wb  : wf;
    const float* bias = dir ? bbv : bfv;
    const int* id2 = ids2 + dir * (B_ * T_);
    us* xgd = xg + (size_t)dir * B_ * T_ * 2048;
    int m0 = mt * 64, n0 = nt * 64;
    __shared__ __align__(16) us As[64][136];
    __shared__ __align__(16) us Bs[64][136];
    int tid = threadIdx.x;
    int wv = tid >> 6, lane = tid & 63;
    int lm = lane & 15, lg = lane >> 4;
    f32x4 z = {0.f, 0.f, 0.f, 0.f};
    f32x4 acc[4] = {z, z, z, z};
    for (int half = 0; half < 2; ++half) {
        for (int c = tid; c < 1024; c += 256) {
            int row = c >> 4, cb = c & 15;
            int mg = m0 + row;
            int j = mg >> 2, g = mg & 3;
            *(uint4*)&As[row][cb * 8] =
                *(const uint4*)(W + ((size_t)(g * H_ + j)) * E_ + half * 128 + cb * 8);
            int gi = id2[n0 + row];
            *(uint4*)&Bs[row][cb * 8] =
                *(const uint4*)(emb + (size_t)gi * E_ + half * 128 + cb * 8);
        }
        __syncthreads();
#pragma unroll
        for (int kt = 0; kt < 4; ++kt) {
            short8 a = *(const short8*)&As[wv * 16 + lm][kt * 32 + lg * 8];
#pragma unroll
            for (int n2 = 0; n2 < 4; ++n2) {
                short8 b = *(const short8*)&Bs[n2 * 16 + lm][kt * 32 + lg * 8];
                acc[n2] = __builtin_amdgcn_mfma_f32_16x16x32_bf16(a, b, acc[n2], 0, 0, 0);
            }
        }
        __syncthreads();
    }
    int jgb = m0 + wv * 16 + lg * 4;
    int j = jgb >> 2;
#pragma unroll
    for (int n2 = 0; n2 < 4; ++n2) {
        int token = n0 + n2 * 16 + lm;
        us p[4];
#pragma unroll
        for (int q = 0; q < 4; ++q)
            p[q] = f2bf(acc[n2][q] + bias[q * H_ + j]);
        uint2 pv;
        pv.x = (uint32_t)p[0] | ((uint32_t)p[1] << 16);
        pv.y = (uint32_t)p[2] | ((uint32_t)p[3] << 16);
        *(uint2*)(xgd + (size_t)token * 2048 + jgb) = pv;
    }
}

// ---------------------------------------------------------------------------
// Kernel 3: persistent BiLSTM — round-9 structure + END-of-loop xg prefetch.
// 64 wgs: dir=bid>>5, slice w=bid&31 (16 hidden j each). W slice 64 KB LDS
// (XOR-swizzled). Per step: wave0 polls 32 padded wg-slots -> barrier ->
// h u64 atomic loads -> unpack xg (prefetched regs) -> MFMA -> cell ->
// Hx repack + hod stores -> barrier -> coalesced atomicExch publish ->
// barrier -> slot atomicExch -> NEXT-step xg prefetch (drains under the
// next poll window, off the h-load/MFMA chain).
__launch_bounds__(256)
__global__ void k_lstm(const us* __restrict__ whf, const us* __restrict__ whb,
                       const us* __restrict__ xg,
                       us* __restrict__ h_state, us* __restrict__ h_out,
                       int* __restrict__ flags, int* __restrict__ marker) {
    int bid = blockIdx.x;
    int dir = bid >> 5, w = bid & 31;
    int tid = threadIdx.x;
    if (bid == 0 && tid == 0) atomicOr(marker, 4);
    const us* Wg = dir ? whb : whf;
    __shared__ __align__(16) us Ws[64 * 512];   // 65536 B, swizzled
    __shared__ __align__(4)  us Hx[32 * 16];    // h repack [b][j_loc], 1 KB
    for (int c = tid; c < 4096; c += 256) {      // 4096 x 16B chunks
        int row = c >> 6, cb = c & 63;
        int rt = row >> 4, rl = row & 15;
        int jj = rl >> 2, g = rl & 3;
        int srcRow = g * H_ + w * 16 + rt * 4 + jj;
        uint4 v = *(const uint4*)(Wg + (size_t)srcRow * H_ + cb * 8);
        int lb = row * 1024 + ((cb * 16) ^ ((row & 7) << 4));
        *(uint4*)((char*)Ws + lb) = v;
    }
    __syncthreads();
    int wv = tid >> 6, lane = tid & 63;
    int nb = wv & 1, rh = wv >> 1;               // batch-half, row-half
    int lm = lane & 15, lg = lane >> 4;
    int b = nb * 16 + lm;                        // this lane's batch (N index)
    int jl0 = rh * 8 + lg;                       // ti=0 local j
    int jl1 = rh * 8 + 4 + lg;                   // ti=1 local j
    const us* xgd = xg + (size_t)dir * B_ * T_ * 2048;
    us* hod = h_out + (size_t)dir * B_ * T_ * H_;
    int* slots = flags + dir * 512;              // 32 slots, stride 16 ints
    const uint64_t* hbase = (const uint64_t*)h_state + (size_t)dir * 8192;
    uint32_t* hw32 = (uint32_t*)h_state + (size_t)dir * 16384;
    float cc0 = 0.f, cc1 = 0.f;
    bool alive = true;
    // prologue: prefetch xg for t=0
    uint2 vr0 = *(const uint2*)(xgd + ((size_t)b) * 2048 + (w * 16 + jl0) * 4);
    uint2 vr1 = *(const uint2*)(xgd + ((size_t)b) * 2048 + (w * 16 + jl1) * 4);
#pragma unroll 1
    for (int t = 0; t < T_; ++t) {
        f32x4 acc[2];
        if (t > 0) {
            if (wv == 0) {                       // wave 0: parallel 32-slot poll
                int polls = 0;
                for (;;) {
                    int v = (lane < 32)
                        ? __hip_atomic_load(&slots[lane * 16], __ATOMIC_RELAXED, __HIP_MEMORY_SCOPE_AGENT)
                        : 0x7fffffff;
                    if (__all(v >= t) || !alive) break;
                    __builtin_amdgcn_s_sleep(1);
                    if (++polls > 300000) {      // fail loud, not hung
                        if (lane == 0) atomicOr(marker, 32);
                        alive = false;
                    }
                }
            }
            __syncthreads();                     // also drains last prefetch
            // coherent h_{t-1} loads (u64 AGENT atomics = L2-bypass)
            const uint64_t* hp = hbase + ((t - 1) & 1) * 4096 + (size_t)b * 128 + lg * 2;
            uint64_t hv[32];
#pragma unroll
            for (int kt = 0; kt < 16; ++kt) {
                hv[2 * kt]     = __hip_atomic_load(hp + kt * 8,     __ATOMIC_RELAXED, __HIP_MEMORY_SCOPE_AGENT);
                hv[2 * kt + 1] = __hip_atomic_load(hp + kt * 8 + 1, __ATOMIC_RELAXED, __HIP_MEMORY_SCOPE_AGENT);
            }
            // unpack xg (registers, prefetched last step) under the load shadow
            acc[0][0] = bf2f(vr0.x & 0xffff); acc[0][1] = bf2f(vr0.x >> 16);
            acc[0][2] = bf2f(vr0.y & 0xffff); acc[0][3] = bf2f(vr0.y >> 16);
            acc[1][0] = bf2f(vr1.x & 0xffff); acc[1][1] = bf2f(vr1.x >> 16);
            acc[1][2] = bf2f(vr1.y & 0xffff); acc[1][3] = bf2f(vr1.y >> 16);
#pragma unroll
            for (int ti = 0; ti < 2; ++ti) {
                int r0 = (rh * 2 + ti) * 16 + lm;
                const char* abase = (const char*)Ws + r0 * 1024;
                int sw = (r0 & 7) << 4;
#pragma unroll
                for (int kt = 0; kt < 16; ++kt) {
                    union { uint64_t u[2]; short8 s; } bu;
                    bu.u[0] = hv[2 * kt]; bu.u[1] = hv[2 * kt + 1];
                    short8 a = *(const short8*)(abase + ((kt * 64 + lg * 16) ^ sw));
                    acc[ti] = __builtin_amdgcn_mfma_f32_16x16x32_bf16(a, bu.s, acc[ti], 0, 0, 0);
                }
            }
        } else {
            acc[0][0] = bf2f(vr0.x & 0xffff); acc[0][1] = bf2f(vr0.x >> 16);
            acc[0][2] = bf2f(vr0.y & 0xffff); acc[0][3] = bf2f(vr0.y >> 16);
            acc[1][0] = bf2f(vr1.x & 0xffff); acc[1][1] = bf2f(vr1.x >> 16);
            acc[1][2] = bf2f(vr1.y & 0xffff); acc[1][3] = bf2f(vr1.y >> 16);
        }
        // cell update (acc[ti][q]: q = gate, torch order i,f,g,o)
        cc0 = sigf(acc[0][1]) * cc0 + sigf(acc[0][0]) * tanhf_(acc[0][2]);
        float h0 = sigf(acc[0][3]) * tanhf_(cc0);
        cc1 = sigf(acc[1][1]) * cc1 + sigf(acc[1][0]) * tanhf_(acc[1][2]);
        float h1 = sigf(acc[1][3]) * tanhf_(cc1);
        us p0 = f2bf(h0), p1 = f2bf(h1);
        Hx[b * 16 + jl0] = p0;
        Hx[b * 16 + jl1] = p1;
        hod[((size_t)b * T_ + t) * H_ + w * 16 + jl0] = p0;
        hod[((size_t)b * T_ + t) * H_ + w * 16 + jl1] = p1;
        __syncthreads();                          // Hx complete; parity reads done
        {   // coalesced publish: 8 consecutive u32 per 8 threads
            uint32_t v = ((const uint32_t*)Hx)[tid];
            int bb = tid >> 3, jp = tid & 7;
            atomicExch(&hw32[(size_t)(t & 1) * 8192 + (size_t)bb * 256 + w * 8 + jp], v);
        }
        __syncthreads();                          // drains vmcnt: publishes complete
        if (tid == 0) atomicExch(&slots[w * 16], t + 1);
        // END-of-loop prefetch: flies under next step's poll window
        if (t + 1 < T_) {
            vr0 = *(const uint2*)(xgd + ((size_t)((t + 1) * 32 + b)) * 2048 + (w * 16 + jl0) * 4);
            vr1 = *(const uint2*)(xgd + ((size_t)((t + 1) * 32 + b)) * 2048 + (w * 16 + jl1) * 4);
        }
    }
}

// ---------------------------------------------------------------------------
// Kernel 4: emissions[b*T+t][k] = [hf(b,t), hb(b,rev)] . w_cls[k] + b_cls[k]
__launch_bounds__(256)
__global__ void k_emis(const us* __restrict__ h_out,
                       const us* __restrict__ wcls, const float* __restrict__ bcls,
                       const int* __restrict__ lengths, float* __restrict__ emis,
                       int* __restrict__ marker) {
    if (blockIdx.x == 0 && threadIdx.x == 0) atomicOr(marker, 8);
    __shared__ __align__(8) us Wc[17][1032];
    int tid = threadIdx.x;
    for (int c = tid; c < 17 * 256; c += 256) {
        int row = c >> 8; int c4 = (c & 255) * 4;
        *(uint2*)&Wc[row][c4] = *(const uint2*)(wcls + (size_t)row * 1024 + c4);
    }
    __syncthreads();
    int i = blockIdx.x * 8 + (tid >> 5);
    int k = tid & 31;
    int b = i >> 9, t = i & 511;
    int l = lengths[b];
    int trv = (t < l) ? (l - 1 - t) : t;
    const us* hf = h_out + ((size_t)(0 * B_ + b) * T_ + t) * H_;
    const us* hb = h_out + ((size_t)(1 * B_ + b) * T_ + trv) * H_;
    if (k < K_) {
        float acc = bcls[k];
        for (int e = 0; e < H_; e += 4) {
            uint2 hv = *(const uint2*)(hf + e);
            uint2 wv = *(const uint2*)&Wc[k][e];
            acc = fmaf(bf2f(hv.x & 0xffff), bf2f(wv.x & 0xffff), acc);
            acc = fmaf(bf2f(hv.x >> 16),    bf2f(wv.x >> 16),    acc);
            acc = fmaf(bf2f(hv.y & 0xffff), bf2f(wv.y & 0xffff), acc);
            acc = fmaf(bf2f(hv.y >> 16),    bf2f(wv.y >> 16),    acc);
        }
        for (int e = 0; e < H_; e += 4) {
            uint2 hv = *(const uint2*)(hb + e);
            uint2 wv = *(const uint2*)&Wc[k][512 + e];
            acc = fmaf(bf2f(hv.x & 0xffff), bf2f(wv.x & 0xffff), acc);
            acc = fmaf(bf2f(hv.x >> 16),    bf2f(wv.x >> 16),    acc);
            acc = fmaf(bf2f(hv.y & 0xffff), bf2f(wv.y & 0xffff), acc);
            acc = fmaf(bf2f(hv.y >> 16),    bf2f(wv.y >> 16),    acc);
        }
        emis[(size_t)i * 20 + k] = acc;
    }
}

// ---------------------------------------------------------------------------
// Kernel 5: CRF per batch, 1 wave, register-resident forward recursion.
__global__ void k_crf(const float* __restrict__ emis, const int* __restrict__ tags,
                      const int* __restrict__ lengths,
                      const float* __restrict__ start_t, const float* __restrict__ trans_t,
                      const float* __restrict__ end_t, float* __restrict__ res,
                      int* __restrict__ marker) {
    if (blockIdx.x == 0 && threadIdx.x == 0) atomicOr(marker, 16);
    __shared__ float tr[17][18];
    int b = blockIdx.x, tid = threadIdx.x;
    for (int i = tid; i < 289; i += 64) tr[i / 17][i % 17] = trans_t[i];
    __syncthreads();
    int l = lengths[b];
    const int* tg = tags + b * T_;
    const float* eb = emis + (size_t)b * T_ * 20;
    float sn = 0.f;
    for (int t = tid; t < T_; t += 64) {
        if (t < l) {
            sn += eb[t * 20 + tg[t]];
            if (t >= 1) sn += tr[tg[t - 1]][tg[t]];
        }
    }
#pragma unroll
    for (int off = 32; off; off >>= 1) sn += __shfl_xor(sn, off, 64);
    float numer = sn + start_t[tg[0]] + end_t[tg[l - 1]];
    int k = (tid < K_) ? tid : (K_ - 1);
    float trc[17];
#pragma unroll
    for (int j = 0; j < 17; ++j) trc[j] = trans_t[j * 17 + k];
    float alpha = start_t[k] + eb[k];
    for (int t = 1; t < l; ++t) {
        float av[17];
        float m = -1e30f;
#pragma unroll
        for (int j = 0; j < 17; ++j) {
            av[j] = __shfl(alpha, j) + trc[j];
            m = fmaxf(m, av[j]);
        }
        float s = 0.f;
#pragma unroll
        for (int j = 0; j < 17; ++j) s += __expf(av[j] - m);
        alpha = m + __logf(s) + eb[t * 20 + k];
    }
    float v = (tid < K_) ? (alpha + end_t[tid]) : -1e30f;
    float m2 = v;
#pragma unroll
    for (int off = 32; off; off >>= 1) m2 = fmaxf(m2, __shfl_xor(m2, off, 64));
    float s2 = __expf(v - m2);
#pragma unroll
    for (int off = 32; off; off >>= 1) s2 += __shfl_xor(s2, off, 64);
    if (tid == 0) res[b] = numer - (m2 + __logf(s2));
}

// ---------------------------------------------------------------------------
// Kernel 6 (LAST): float32 output, negative diagnostic codes:
//   hm!=0 -> -(16384+512*hm) ; dm!=31 -> -(8192+128*(dm&63)) ;
//   NaN in res[b] -> -(4096+b) ; else loss (positive ~1048).
__global__ void k_fin(const float* __restrict__ res, int* __restrict__ marker,
                      int hostmask, float* __restrict__ out) {
    int tid = threadIdx.x;
    if (hostmask != 0) {
        if (tid == 0) out[0] = -(16384.0f + 512.0f * (float)hostmask);
        return;
    }
    int dm = atomicOr(marker, 0);
    if (dm != 31) {
        if (tid == 0) out[0] = -(8192.0f + 128.0f * (float)(dm & 63));
        return;
    }
    float v = (tid < B_) ? res[tid] : 0.f;
    unsigned long long nb = __ballot(v != v);
    if (nb != 0ULL) {
        if (tid == 0) out[0] = -(4096.0f + (float)(__ffsll((long long)nb) - 1));
        return;
    }
#pragma unroll
    for (int off = 32; off; off >>= 1) v += __shfl_xor(v, off, 64);
    if (tid == 0) out[0] = -(v / (float)B_);
}

// ---------------------------------------------------------------------------
extern "C" void kernel_launch(void* const* d_in, const int* in_sizes, int n_in,
                              void* d_out, int out_size, void* d_ws, size_t ws_size,
                              hipStream_t stream) {
    const int* ids      = (const int*)d_in[0];
    const int* lengths  = (const int*)d_in[1];
    const int* tags     = (const int*)d_in[2];
    // d_in[3] = mask (recomputed from lengths)
    const float* emb_f  = (const float*)d_in[4];
    const float* wihf_f = (const float*)d_in[5];
    const float* whhf_f = (const float*)d_in[6];
    const float* bfv    = (const float*)d_in[7];
    const float* wihb_f = (const float*)d_in[8];
    const float* whhb_f = (const float*)d_in[9];
    const float* bbv    = (const float*)d_in[10];
    const float* wcls_f = (const float*)d_in[11];
    const float* bcls   = (const float*)d_in[12];
    const float* start  = (const float*)d_in[13];
    const float* trans  = (const float*)d_in[14];
    const float* endt   = (const float*)d_in[15];
    float* out = (float*)d_out;

    // host-side validation (element counts)
    int hm = 0;
    if (n_in != 16 || out_size != 1) hm |= 8;
    const int exp_sz[16] = {
        16384, 32, 16384, 16384,
        12800000,
        524288, 1048576, 2048,
        524288, 1048576, 2048,
        17408, 17,
        17, 289, 17
    };
    if (!(hm & 8))
        for (int i = 0; i < 16; ++i)
            if (in_sizes[i] != exp_sz[i]) hm |= 2;

    // workspace carve (256B aligned)
    char* w = (char*)d_ws;
    size_t off = 0;
    auto carve = [&](size_t bytes) { void* p = w + off; off += (bytes + 255) & ~(size_t)255; return p; };
    int* ids2    = (int*)carve((size_t)2 * B_ * T_ * 4);
    int* marker  = (int*)carve(256);
    int* flags   = (int*)carve(4096);            // 2 dirs x 32 slots x 64 B pad
    float* res   = (float*)carve(256);
    float* emis  = (float*)carve((size_t)B_ * T_ * 20 * 4);
    us* xg       = (us*)carve((size_t)2 * B_ * T_ * 2048 * 2);
    us* h_st     = (us*)carve((size_t)2 * 2 * B_ * H_ * 2);
    us* h_out    = (us*)carve((size_t)2 * B_ * T_ * H_ * 2);
    us* emb_b    = (us*)carve((size_t)12800000 * 2);
    us* wihf_b   = (us*)carve((size_t)524288 * 2);
    us* wihb_b   = (us*)carve((size_t)524288 * 2);
    us* whhf_b   = (us*)carve((size_t)1048576 * 2);
    us* whhb_b   = (us*)carve((size_t)1048576 * 2);
    us* wcls_b   = (us*)carve((size_t)17408 * 2);
    if (off > ws_size) hm |= 4;

    (void)hipGetLastError();
    if ((hm & (2 | 4 | 8)) == 0) {
        k_init<<<(2 * B_ * T_ + 255) / 256, 256, 0, stream>>>(ids, lengths, ids2, marker, flags, out);
        // f32 -> bf16 conversions
        k_cvt<<<(12800000 / 4 + 255) / 256, 256, 0, stream>>>(emb_f,  emb_b,  12800000 / 4);
        k_cvt<<<(524288   / 4 + 255) / 256, 256, 0, stream>>>(wihf_f, wihf_b, 524288 / 4);
        k_cvt<<<(524288   / 4 + 255) / 256, 256, 0, stream>>>(wihb_f, wihb_b, 524288 / 4);
        k_cvt<<<(1048576  / 4 + 255) / 256, 256, 0, stream>>>(whhf_f, whhf_b, 1048576 / 4);
        k_cvt<<<(1048576  / 4 + 255) / 256, 256, 0, stream>>>(whhb_f, whhb_b, 1048576 / 4);
        k_cvt<<<(17408    / 4 + 255) / 256, 256, 0, stream>>>(wcls_f, wcls_b, 17408 / 4);
        k_xg<<<dim3(2048 / 64, B_ * T_ / 64, 2), 256, 0, stream>>>(emb_b, wihf_b, bfv, wihb_b, bbv, ids2, xg, marker);
        k_lstm<<<64, 256, 0, stream>>>(whhf_b, whhb_b, xg, h_st, h_out, flags, marker);
        k_emis<<<B_ * T_ / 8, 256, 0, stream>>>(h_out, wcls_b, bcls, lengths, emis, marker);
        k_crf<<<B_, 64, 0, stream>>>(emis, tags, lengths, start, trans, endt, res, marker);
        if (hipGetLastError() != hipSuccess) hm |= 1;
    }
    k_fin<<<1, 64, 0, stream>>>(res, marker, hm, out);
}

// Round 15
// 2883.083 us; speedup vs baseline: 1.1711x; 1.0508x over previous
//
#include <hip/hip_runtime.h>
#include <hip/hip_bf16.h>
#include <stdint.h>

// Problem dims
#define B_  32
#define T_  512
#define E_  256
#define H_  512
#define K_  17
// 4H = 2048

typedef unsigned short us;
typedef __attribute__((ext_vector_type(8))) short short8;
typedef __attribute__((ext_vector_type(4))) float f32x4;

__device__ __forceinline__ float bf2f(unsigned int u16) {
    union { unsigned int i; float f; } v; v.i = u16 << 16; return v.f;
}
__device__ __forceinline__ us f2bf(float f) {
    union { float f; unsigned int i; } v; v.f = f;
    unsigned int b = v.i;
    return (us)((b + 0x7FFFu + ((b >> 16) & 1u)) >> 16);
}
__device__ __forceinline__ float sigf(float x) { return 1.0f / (1.0f + __expf(-x)); }
__device__ __forceinline__ float tanhf_(float x) { return 1.0f - 2.0f / (__expf(2.0f * x) + 1.0f); }

// ---------------------------------------------------------------------------
// Kernel 0: float32 -> bf16 conversion (RNE), 4 elements/thread.
__global__ void k_cvt(const float* __restrict__ src, us* __restrict__ dst, int n4) {
    int i = blockIdx.x * 256 + threadIdx.x;
    if (i < n4) {
        float4 v = ((const float4*)src)[i];
        uint2 p;
        p.x = (uint32_t)f2bf(v.x) | ((uint32_t)f2bf(v.y) << 16);
        p.y = (uint32_t)f2bf(v.z) | ((uint32_t)f2bf(v.w) << 16);
        ((uint2*)dst)[i] = p;
    }
}

// ---------------------------------------------------------------------------
// Kernel 1: sentinel + marker/slot init + gathered token-index table.
// ids2 layout: [dir][t*B + b]
__global__ void k_init(const int* __restrict__ ids, const int* __restrict__ lengths,
                       int* __restrict__ ids2, int* __restrict__ marker,
                       int* __restrict__ flags, float* __restrict__ out) {
    int idx = blockIdx.x * 256 + threadIdx.x;
    if (idx == 0) { *marker = 1; out[0] = -3328.0f; }
    if (idx < 1024) flags[idx] = 0;             // 2 dirs x 32 slots x 16-int pad
    if (idx < 2 * B_ * T_) {
        int dir = idx >> 14;           // 16384 per dir
        int r   = idx & 16383;
        int t   = r >> 5;              // t-major, B=32
        int b   = r & 31;
        int l   = lengths[b];
        int tt  = (dir == 0) ? t : ((t < l) ? (l - 1 - t) : t);
        ids2[idx] = ids[b * T_ + tt];
    }
}

// ---------------------------------------------------------------------------
// Kernel 2: xg[dir][t*B+b][jg] = (emb[ids2] @ W_ih^T + bias), permuted layout
// jg = j*4 + g  (torch gates i,f,g,o contiguous per hidden index j).
__launch_bounds__(256)
__global__ void k_xg(const us* __restrict__ emb,
                     const us* __restrict__ wf, const float* __restrict__ bfv,
                     const us* __restrict__ wb, const float* __restrict__ bbv,
                     const int* __restrict__ ids2, us* __restrict__ xg,
                     int* __restrict__ marker) {
    if (blockIdx.x == 0 && blockIdx.y == 0 && blockIdx.z == 0 && threadIdx.x == 0)
        atomicOr(marker, 2);
    int mt = blockIdx.x, nt = blockIdx.y, dir = blockIdx.z;
    const us* W      = dir ? wb  : wf;
    const float* bias = dir ? bbv : bfv;
    const int* id2 = ids2 + dir * (B_ * T_);
    us* xgd = xg + (size_t)dir * B_ * T_ * 2048;
    int m0 = mt * 64, n0 = nt * 64;
    __shared__ __align__(16) us As[64][136];
    __shared__ __align__(16) us Bs[64][136];
    int tid = threadIdx.x;
    int wv = tid >> 6, lane = tid & 63;
    int lm = lane & 15, lg = lane >> 4;
    f32x4 z = {0.f, 0.f, 0.f, 0.f};
    f32x4 acc[4] = {z, z, z, z};
    for (int half = 0; half < 2; ++half) {
        for (int c = tid; c < 1024; c += 256) {
            int row = c >> 4, cb = c & 15;
            int mg = m0 + row;
            int j = mg >> 2, g = mg & 3;
            *(uint4*)&As[row][cb * 8] =
                *(const uint4*)(W + ((size_t)(g * H_ + j)) * E_ + half * 128 + cb * 8);
            int gi = id2[n0 + row];
            *(uint4*)&Bs[row][cb * 8] =
                *(const uint4*)(emb + (size_t)gi * E_ + half * 128 + cb * 8);
        }
        __syncthreads();
#pragma unroll
        for (int kt = 0; kt < 4; ++kt) {
            short8 a = *(const short8*)&As[wv * 16 + lm][kt * 32 + lg * 8];
#pragma unroll
            for (int n2 = 0; n2 < 4; ++n2) {
                short8 b = *(const short8*)&Bs[n2 * 16 + lm][kt * 32 + lg * 8];
                acc[n2] = __builtin_amdgcn_mfma_f32_16x16x32_bf16(a, b, acc[n2], 0, 0, 0);
            }
        }
        __syncthreads();
    }
    int jgb = m0 + wv * 16 + lg * 4;
    int j = jgb >> 2;
#pragma unroll
    for (int n2 = 0; n2 < 4; ++n2) {
        int token = n0 + n2 * 16 + lm;
        us p[4];
#pragma unroll
        for (int q = 0; q < 4; ++q)
            p[q] = f2bf(acc[n2][q] + bias[q * H_ + j]);
        uint2 pv;
        pv.x = (uint32_t)p[0] | ((uint32_t)p[1] << 16);
        pv.y = (uint32_t)p[2] | ((uint32_t)p[3] << 16);
        *(uint2*)(xgd + (size_t)token * 2048 + jgb) = pv;
    }
}

// ---------------------------------------------------------------------------
// Kernel 3: persistent BiLSTM — round-14 structure + XCD co-location probe.
// Launch 256 wgs; role r = bid&7: r<2 -> dir=r, slice w=bid>>3; r>=2 -> exit.
// Under round-robin wg->XCD (bid%8), each direction's 32 wgs share ONE XCD,
// so the agent-scope h/slot traffic is serviced by the local L2 instead of
// the MALL. Protocol unchanged -> correctness placement-independent.
__launch_bounds__(256)
__global__ void k_lstm(const us* __restrict__ whf, const us* __restrict__ whb,
                       const us* __restrict__ xg,
                       us* __restrict__ h_state, us* __restrict__ h_out,
                       int* __restrict__ flags, int* __restrict__ marker) {
    int bid = blockIdx.x;
    int role = bid & 7;
    int tid = threadIdx.x;
    if (bid == 0 && tid == 0) atomicOr(marker, 4);
    if (role >= 2) return;                       // passive wg (placement filler)
    int dir = role, w = bid >> 3;                // w in 0..31
    const us* Wg = dir ? whb : whf;
    __shared__ __align__(16) us Ws[64 * 512];   // 65536 B, swizzled
    __shared__ __align__(4)  us Hx[32 * 16];    // h repack [b][j_loc], 1 KB
    for (int c = tid; c < 4096; c += 256) {      // 4096 x 16B chunks
        int row = c >> 6, cb = c & 63;
        int rt = row >> 4, rl = row & 15;
        int jj = rl >> 2, g = rl & 3;
        int srcRow = g * H_ + w * 16 + rt * 4 + jj;
        uint4 v = *(const uint4*)(Wg + (size_t)srcRow * H_ + cb * 8);
        int lb = row * 1024 + ((cb * 16) ^ ((row & 7) << 4));
        *(uint4*)((char*)Ws + lb) = v;
    }
    __syncthreads();
    int wv = tid >> 6, lane = tid & 63;
    int nb = wv & 1, rh = wv >> 1;               // batch-half, row-half
    int lm = lane & 15, lg = lane >> 4;
    int b = nb * 16 + lm;                        // this lane's batch (N index)
    int jl0 = rh * 8 + lg;                       // ti=0 local j
    int jl1 = rh * 8 + 4 + lg;                   // ti=1 local j
    const us* xgd = xg + (size_t)dir * B_ * T_ * 2048;
    us* hod = h_out + (size_t)dir * B_ * T_ * H_;
    int* slots = flags + dir * 512;              // 32 slots, stride 16 ints
    const uint64_t* hbase = (const uint64_t*)h_state + (size_t)dir * 8192;
    uint32_t* hw32 = (uint32_t*)h_state + (size_t)dir * 16384;
    float cc0 = 0.f, cc1 = 0.f;
    bool alive = true;
    // prologue: prefetch xg for t=0
    uint2 vr0 = *(const uint2*)(xgd + ((size_t)b) * 2048 + (w * 16 + jl0) * 4);
    uint2 vr1 = *(const uint2*)(xgd + ((size_t)b) * 2048 + (w * 16 + jl1) * 4);
#pragma unroll 1
    for (int t = 0; t < T_; ++t) {
        f32x4 acc[2];
        if (t > 0) {
            if (wv == 0) {                       // wave 0: parallel 32-slot poll
                int polls = 0;
                for (;;) {
                    int v = (lane < 32)
                        ? __hip_atomic_load(&slots[lane * 16], __ATOMIC_RELAXED, __HIP_MEMORY_SCOPE_AGENT)
                        : 0x7fffffff;
                    if (__all(v >= t) || !alive) break;
                    __builtin_amdgcn_s_sleep(1);
                    if (++polls > 300000) {      // fail loud, not hung
                        if (lane == 0) atomicOr(marker, 32);
                        alive = false;
                    }
                }
            }
            __syncthreads();                     // also drains last prefetch
            // coherent h_{t-1} loads (u64 AGENT atomics)
            const uint64_t* hp = hbase + ((t - 1) & 1) * 4096 + (size_t)b * 128 + lg * 2;
            uint64_t hv[32];
#pragma unroll
            for (int kt = 0; kt < 16; ++kt) {
                hv[2 * kt]     = __hip_atomic_load(hp + kt * 8,     __ATOMIC_RELAXED, __HIP_MEMORY_SCOPE_AGENT);
                hv[2 * kt + 1] = __hip_atomic_load(hp + kt * 8 + 1, __ATOMIC_RELAXED, __HIP_MEMORY_SCOPE_AGENT);
            }
            // unpack xg (registers, prefetched last step) under the load shadow
            acc[0][0] = bf2f(vr0.x & 0xffff); acc[0][1] = bf2f(vr0.x >> 16);
            acc[0][2] = bf2f(vr0.y & 0xffff); acc[0][3] = bf2f(vr0.y >> 16);
            acc[1][0] = bf2f(vr1.x & 0xffff); acc[1][1] = bf2f(vr1.x >> 16);
            acc[1][2] = bf2f(vr1.y & 0xffff); acc[1][3] = bf2f(vr1.y >> 16);
#pragma unroll
            for (int ti = 0; ti < 2; ++ti) {
                int r0 = (rh * 2 + ti) * 16 + lm;
                const char* abase = (const char*)Ws + r0 * 1024;
                int sw = (r0 & 7) << 4;
#pragma unroll
                for (int kt = 0; kt < 16; ++kt) {
                    union { uint64_t u[2]; short8 s; } bu;
                    bu.u[0] = hv[2 * kt]; bu.u[1] = hv[2 * kt + 1];
                    short8 a = *(const short8*)(abase + ((kt * 64 + lg * 16) ^ sw));
                    acc[ti] = __builtin_amdgcn_mfma_f32_16x16x32_bf16(a, bu.s, acc[ti], 0, 0, 0);
                }
            }
        } else {
            acc[0][0] = bf2f(vr0.x & 0xffff); acc[0][1] = bf2f(vr0.x >> 16);
            acc[0][2] = bf2f(vr0.y & 0xffff); acc[0][3] = bf2f(vr0.y >> 16);
            acc[1][0] = bf2f(vr1.x & 0xffff); acc[1][1] = bf2f(vr1.x >> 16);
            acc[1][2] = bf2f(vr1.y & 0xffff); acc[1][3] = bf2f(vr1.y >> 16);
        }
        // cell update (acc[ti][q]: q = gate, torch order i,f,g,o)
        cc0 = sigf(acc[0][1]) * cc0 + sigf(acc[0][0]) * tanhf_(acc[0][2]);
        float h0 = sigf(acc[0][3]) * tanhf_(cc0);
        cc1 = sigf(acc[1][1]) * cc1 + sigf(acc[1][0]) * tanhf_(acc[1][2]);
        float h1 = sigf(acc[1][3]) * tanhf_(cc1);
        us p0 = f2bf(h0), p1 = f2bf(h1);
        Hx[b * 16 + jl0] = p0;
        Hx[b * 16 + jl1] = p1;
        hod[((size_t)b * T_ + t) * H_ + w * 16 + jl0] = p0;
        hod[((size_t)b * T_ + t) * H_ + w * 16 + jl1] = p1;
        __syncthreads();                          // Hx complete; parity reads done
        {   // coalesced publish: 8 consecutive u32 per 8 threads
            uint32_t v = ((const uint32_t*)Hx)[tid];
            int bb = tid >> 3, jp = tid & 7;
            atomicExch(&hw32[(size_t)(t & 1) * 8192 + (size_t)bb * 256 + w * 8 + jp], v);
        }
        __syncthreads();                          // drains vmcnt: publishes complete
        if (tid == 0) atomicExch(&slots[w * 16], t + 1);
        // END-of-loop prefetch: flies under next step's poll window
        if (t + 1 < T_) {
            vr0 = *(const uint2*)(xgd + ((size_t)((t + 1) * 32 + b)) * 2048 + (w * 16 + jl0) * 4);
            vr1 = *(const uint2*)(xgd + ((size_t)((t + 1) * 32 + b)) * 2048 + (w * 16 + jl1) * 4);
        }
    }
}

// ---------------------------------------------------------------------------
// Kernel 4: emissions[b*T+t][k] = [hf(b,t), hb(b,rev)] . w_cls[k] + b_cls[k]
__launch_bounds__(256)
__global__ void k_emis(const us* __restrict__ h_out,
                       const us* __restrict__ wcls, const float* __restrict__ bcls,
                       const int* __restrict__ lengths, float* __restrict__ emis,
                       int* __restrict__ marker) {
    if (blockIdx.x == 0 && threadIdx.x == 0) atomicOr(marker, 8);
    __shared__ __align__(8) us Wc[17][1032];
    int tid = threadIdx.x;
    for (int c = tid; c < 17 * 256; c += 256) {
        int row = c >> 8; int c4 = (c & 255) * 4;
        *(uint2*)&Wc[row][c4] = *(const uint2*)(wcls + (size_t)row * 1024 + c4);
    }
    __syncthreads();
    int i = blockIdx.x * 8 + (tid >> 5);
    int k = tid & 31;
    int b = i >> 9, t = i & 511;
    int l = lengths[b];
    int trv = (t < l) ? (l - 1 - t) : t;
    const us* hf = h_out + ((size_t)(0 * B_ + b) * T_ + t) * H_;
    const us* hb = h_out + ((size_t)(1 * B_ + b) * T_ + trv) * H_;
    if (k < K_) {
        float acc = bcls[k];
        for (int e = 0; e < H_; e += 4) {
            uint2 hv = *(const uint2*)(hf + e);
            uint2 wv = *(const uint2*)&Wc[k][e];
            acc = fmaf(bf2f(hv.x & 0xffff), bf2f(wv.x & 0xffff), acc);
            acc = fmaf(bf2f(hv.x >> 16),    bf2f(wv.x >> 16),    acc);
            acc = fmaf(bf2f(hv.y & 0xffff), bf2f(wv.y & 0xffff), acc);
            acc = fmaf(bf2f(hv.y >> 16),    bf2f(wv.y >> 16),    acc);
        }
        for (int e = 0; e < H_; e += 4) {
            uint2 hv = *(const uint2*)(hb + e);
            uint2 wv = *(const uint2*)&Wc[k][512 + e];
            acc = fmaf(bf2f(hv.x & 0xffff), bf2f(wv.x & 0xffff), acc);
            acc = fmaf(bf2f(hv.x >> 16),    bf2f(wv.x >> 16),    acc);
            acc = fmaf(bf2f(hv.y & 0xffff), bf2f(wv.y & 0xffff), acc);
            acc = fmaf(bf2f(hv.y >> 16),    bf2f(wv.y >> 16),    acc);
        }
        emis[(size_t)i * 20 + k] = acc;
    }
}

// ---------------------------------------------------------------------------
// Kernel 5: CRF per batch, 1 wave, register-resident forward recursion.
__global__ void k_crf(const float* __restrict__ emis, const int* __restrict__ tags,
                      const int* __restrict__ lengths,
                      const float* __restrict__ start_t, const float* __restrict__ trans_t,
                      const float* __restrict__ end_t, float* __restrict__ res,
                      int* __restrict__ marker) {
    if (blockIdx.x == 0 && threadIdx.x == 0) atomicOr(marker, 16);
    __shared__ float tr[17][18];
    int b = blockIdx.x, tid = threadIdx.x;
    for (int i = tid; i < 289; i += 64) tr[i / 17][i % 17] = trans_t[i];
    __syncthreads();
    int l = lengths[b];
    const int* tg = tags + b * T_;
    const float* eb = emis + (size_t)b * T_ * 20;
    float sn = 0.f;
    for (int t = tid; t < T_; t += 64) {
        if (t < l) {
            sn += eb[t * 20 + tg[t]];
            if (t >= 1) sn += tr[tg[t - 1]][tg[t]];
        }
    }
#pragma unroll
    for (int off = 32; off; off >>= 1) sn += __shfl_xor(sn, off, 64);
    float numer = sn + start_t[tg[0]] + end_t[tg[l - 1]];
    int k = (tid < K_) ? tid : (K_ - 1);
    float trc[17];
#pragma unroll
    for (int j = 0; j < 17; ++j) trc[j] = trans_t[j * 17 + k];
    float alpha = start_t[k] + eb[k];
    for (int t = 1; t < l; ++t) {
        float av[17];
        float m = -1e30f;
#pragma unroll
        for (int j = 0; j < 17; ++j) {
            av[j] = __shfl(alpha, j) + trc[j];
            m = fmaxf(m, av[j]);
        }
        float s = 0.f;
#pragma unroll
        for (int j = 0; j < 17; ++j) s += __expf(av[j] - m);
        alpha = m + __logf(s) + eb[t * 20 + k];
    }
    float v = (tid < K_) ? (alpha + end_t[tid]) : -1e30f;
    float m2 = v;
#pragma unroll
    for (int off = 32; off; off >>= 1) m2 = fmaxf(m2, __shfl_xor(m2, off, 64));
    float s2 = __expf(v - m2);
#pragma unroll
    for (int off = 32; off; off >>= 1) s2 += __shfl_xor(s2, off, 64);
    if (tid == 0) res[b] = numer - (m2 + __logf(s2));
}

// ---------------------------------------------------------------------------
// Kernel 6 (LAST): float32 output, negative diagnostic codes:
//   hm!=0 -> -(16384+512*hm) ; dm!=31 -> -(8192+128*(dm&63)) ;
//   NaN in res[b] -> -(4096+b) ; else loss (positive ~1048).
__global__ void k_fin(const float* __restrict__ res, int* __restrict__ marker,
                      int hostmask, float* __restrict__ out) {
    int tid = threadIdx.x;
    if (hostmask != 0) {
        if (tid == 0) out[0] = -(16384.0f + 512.0f * (float)hostmask);
        return;
    }
    int dm = atomicOr(marker, 0);
    if (dm != 31) {
        if (tid == 0) out[0] = -(8192.0f + 128.0f * (float)(dm & 63));
        return;
    }
    float v = (tid < B_) ? res[tid] : 0.f;
    unsigned long long nb = __ballot(v != v);
    if (nb != 0ULL) {
        if (tid == 0) out[0] = -(4096.0f + (float)(__ffsll((long long)nb) - 1));
        return;
    }
#pragma unroll
    for (int off = 32; off; off >>= 1) v += __shfl_xor(v, off, 64);
    if (tid == 0) out[0] = -(v / (float)B_);
}

// ---------------------------------------------------------------------------
extern "C" void kernel_launch(void* const* d_in, const int* in_sizes, int n_in,
                              void* d_out, int out_size, void* d_ws, size_t ws_size,
                              hipStream_t stream) {
    const int* ids      = (const int*)d_in[0];
    const int* lengths  = (const int*)d_in[1];
    const int* tags     = (const int*)d_in[2];
    // d_in[3] = mask (recomputed from lengths)
    const float* emb_f  = (const float*)d_in[4];
    const float* wihf_f = (const float*)d_in[5];
    const float* whhf_f = (const float*)d_in[6];
    const float* bfv    = (const float*)d_in[7];
    const float* wihb_f = (const float*)d_in[8];
    const float* whhb_f = (const float*)d_in[9];
    const float* bbv    = (const float*)d_in[10];
    const float* wcls_f = (const float*)d_in[11];
    const float* bcls   = (const float*)d_in[12];
    const float* start  = (const float*)d_in[13];
    const float* trans  = (const float*)d_in[14];
    const float* endt   = (const float*)d_in[15];
    float* out = (float*)d_out;

    // host-side validation (element counts)
    int hm = 0;
    if (n_in != 16 || out_size != 1) hm |= 8;
    const int exp_sz[16] = {
        16384, 32, 16384, 16384,
        12800000,
        524288, 1048576, 2048,
        524288, 1048576, 2048,
        17408, 17,
        17, 289, 17
    };
    if (!(hm & 8))
        for (int i = 0; i < 16; ++i)
            if (in_sizes[i] != exp_sz[i]) hm |= 2;

    // workspace carve (256B aligned)
    char* w = (char*)d_ws;
    size_t off = 0;
    auto carve = [&](size_t bytes) { void* p = w + off; off += (bytes + 255) & ~(size_t)255; return p; };
    int* ids2    = (int*)carve((size_t)2 * B_ * T_ * 4);
    int* marker  = (int*)carve(256);
    int* flags   = (int*)carve(4096);            // 2 dirs x 32 slots x 64 B pad
    float* res   = (float*)carve(256);
    float* emis  = (float*)carve((size_t)B_ * T_ * 20 * 4);
    us* xg       = (us*)carve((size_t)2 * B_ * T_ * 2048 * 2);
    us* h_st     = (us*)carve((size_t)2 * 2 * B_ * H_ * 2);
    us* h_out    = (us*)carve((size_t)2 * B_ * T_ * H_ * 2);
    us* emb_b    = (us*)carve((size_t)12800000 * 2);
    us* wihf_b   = (us*)carve((size_t)524288 * 2);
    us* wihb_b   = (us*)carve((size_t)524288 * 2);
    us* whhf_b   = (us*)carve((size_t)1048576 * 2);
    us* whhb_b   = (us*)carve((size_t)1048576 * 2);
    us* wcls_b   = (us*)carve((size_t)17408 * 2);
    if (off > ws_size) hm |= 4;

    (void)hipGetLastError();
    if ((hm & (2 | 4 | 8)) == 0) {
        k_init<<<(2 * B_ * T_ + 255) / 256, 256, 0, stream>>>(ids, lengths, ids2, marker, flags, out);
        // f32 -> bf16 conversions
        k_cvt<<<(12800000 / 4 + 255) / 256, 256, 0, stream>>>(emb_f,  emb_b,  12800000 / 4);
        k_cvt<<<(524288   / 4 + 255) / 256, 256, 0, stream>>>(wihf_f, wihf_b, 524288 / 4);
        k_cvt<<<(524288   / 4 + 255) / 256, 256, 0, stream>>>(wihb_f, wihb_b, 524288 / 4);
        k_cvt<<<(1048576  / 4 + 255) / 256, 256, 0, stream>>>(whhf_f, whhf_b, 1048576 / 4);
        k_cvt<<<(1048576  / 4 + 255) / 256, 256, 0, stream>>>(whhb_f, whhb_b, 1048576 / 4);
        k_cvt<<<(17408    / 4 + 255) / 256, 256, 0, stream>>>(wcls_f, wcls_b, 17408 / 4);
        k_xg<<<dim3(2048 / 64, B_ * T_ / 64, 2), 256, 0, stream>>>(emb_b, wihf_b, bfv, wihb_b, bbv, ids2, xg, marker);
        k_lstm<<<256, 256, 0, stream>>>(whhf_b, whhb_b, xg, h_st, h_out, flags, marker);
        k_emis<<<B_ * T_ / 8, 256, 0, stream>>>(h_out, wcls_b, bcls, lengths, emis, marker);
        k_crf<<<B_, 64, 0, stream>>>(emis, tags, lengths, start, trans, endt, res, marker);
        if (hipGetLastError() != hipSuccess) hm |= 1;
    }
    k_fin<<<1, 64, 0, stream>>>(res, marker, hm, out);
}